// Round 19
// baseline (116.200 us; speedup 1.0000x reference)
//
#include <hip/hip_runtime.h>

#define SEQ 2048
#define DIM 512
#define HEADS 8
#define HD 64
#define WIN 128
#define NSMAX 320  // 288 band-union + up to 32 global cols
#define KCAT 1536  // 3x bf16-split K
#define QR 32      // query rows per local-attn block

typedef short bf16x8 __attribute__((ext_vector_type(8)));
typedef float f32x4 __attribute__((ext_vector_type(4)));

__device__ inline unsigned short f2bf(float x) {
  unsigned u = __float_as_uint(x);
  unsigned r = (u + 0x7FFF + ((u >> 16) & 1)) >> 16;  // RTNE
  return (unsigned short)r;
}
__device__ inline float bf2f(unsigned short s) {
  return __uint_as_float((unsigned)s << 16);
}

// ---------------- standalone attn zero-fill: NONTEMPORAL stores --------------
// d_out writes measured ~1.5 TB/s via memset/plain stores; R14's NT-fill
// accounting implies NT stores bypass that path (~6 TB/s). A/B test vs R18.
__global__ __launch_bounds__(256) void fill_attn_kernel(float* __restrict__ attn) {
  // 1024 blocks x 256 threads x 32 f32x4 = 134.2 MB
  const size_t base = (size_t)blockIdx.x * 32768 + threadIdx.x * 4;
  const f32x4 z4 = (f32x4)0.0f;
#pragma unroll
  for (int i = 0; i < 32; ++i)
    __builtin_nontemporal_store(z4, (f32x4*)&attn[base + (size_t)i * 1024]);
}

struct WArgs { const float* W[6]; unsigned short* Wc[6]; };

// ---------------- fused prep: convert_x | convert_w | setup ----------------
__global__ __launch_bounds__(256) void prep_kernel(
    const float* __restrict__ X, unsigned short* __restrict__ Xc, WArgs a,
    const int* __restrict__ mask, int* __restrict__ g) {
  const int bid = blockIdx.x;
  const int t = threadIdx.x;

  if (bid < 1024) {  // convert X -> Xcat = [hi | hi | lo]
    const int idx = (bid * 256 + t) * 4;
    const int m = idx >> 9, k = idx & 511;
    const float4 xv = *(const float4*)&X[idx];
    ushort4 hi, lo;
    hi.x = f2bf(xv.x); lo.x = f2bf(xv.x - bf2f(hi.x));
    hi.y = f2bf(xv.y); lo.y = f2bf(xv.y - bf2f(hi.y));
    hi.z = f2bf(xv.z); lo.z = f2bf(xv.z - bf2f(hi.z));
    hi.w = f2bf(xv.w); lo.w = f2bf(xv.w - bf2f(hi.w));
    unsigned short* row = Xc + (size_t)m * KCAT;
    *(ushort4*)&row[k] = hi;
    *(ushort4*)&row[k + 512] = hi;
    *(ushort4*)&row[k + 1024] = lo;
    return;
  }
  if (bid < 2560) {  // convert W_p -> Wcat_p = [hi | lo | hi]
    const int b = bid - 1024;
    const int p = b >> 8;
    const float* __restrict__ W = a.W[p];
    unsigned short* __restrict__ Wc = a.Wc[p];
    const int idx = ((b & 255) * 256 + t) * 4;
    const float4 xv = *(const float4*)&W[idx];
    ushort4 hi, lo;
    hi.x = f2bf(xv.x); lo.x = f2bf(xv.x - bf2f(hi.x));
    hi.y = f2bf(xv.y); lo.y = f2bf(xv.y - bf2f(hi.y));
    hi.z = f2bf(xv.z); lo.z = f2bf(xv.z - bf2f(hi.z));
    hi.w = f2bf(xv.w); lo.w = f2bf(xv.w - bf2f(hi.w));
    unsigned short* row = Wc + (size_t)(idx >> 9) * KCAT;
    const int k = idx & 511;
    *(ushort4*)&row[k] = hi;
    *(ushort4*)&row[k + 512] = lo;
    *(ushort4*)&row[k + 1024] = hi;
    return;
  }
  // setup: ordered compact list of global columns
  {
    __shared__ int wtot[4];
    const int lane = t & 63;
    const int wv = t >> 6;
    int loc[8];
    int n = 0;
    const int base = t * 8;
#pragma unroll
    for (int j = 0; j < 8; ++j) {
      const int c = base + j;
      if (mask[c] == -1) loc[n++] = c;
    }
    int x = n;
#pragma unroll
    for (int o = 1; o < 64; o <<= 1) {
      const int y = __shfl_up(x, o);
      if (lane >= o) x += y;
    }
    if (lane == 63) wtot[wv] = x;
    __syncthreads();
    int basew = 0;
    for (int w = 0; w < wv; ++w) basew += wtot[w];
    if (t == 255) g[0] = basew + x;
    const int off = basew + x - n;
    for (int j = 0; j < n; ++j) g[1 + off + j] = loc[j];
  }
}

// ---------------- MFMA projection GEMM, 2-phase dbuf + global_load_lds -------
struct PMArgs {
  const unsigned short* Wc[6];
  const float* b[6];
  float* out[6];             // fp32 outputs (null = skip)
  unsigned short* outb[6];   // bf16 copies (q,k,v only; else null)
};
__global__ __launch_bounds__(256) void proj_mfma_kernel(
    const unsigned short* __restrict__ Xc, PMArgs a) {
  const int p = blockIdx.z;
  const unsigned short* __restrict__ Wc = a.Wc[p];
  const float* __restrict__ bias = a.b[p];
  float* __restrict__ out = a.out[p];
  unsigned short* __restrict__ outb = a.outb[p];
  const float scale = (p == 0 || p == 3) ? 0.125f : 1.0f;

  __shared__ __align__(16) unsigned short As[2][128 * 64];  // 2 x 16KB
  __shared__ __align__(16) unsigned short Bs[2][64 * 64];   // 2 x 8KB

  const int t = threadIdx.x;
  const int w = t >> 6, l = t & 63;
  const int m0 = blockIdx.x * 128, n0 = blockIdx.y * 64;

  f32x4 acc[2][4];
#pragma unroll
  for (int i = 0; i < 2; ++i)
#pragma unroll
    for (int j = 0; j < 4; ++j) acc[i][j] = (f32x4)0.0f;

  auto stage = [&](int buf, int k0) {
#pragma unroll
    for (int i = 0; i < 4; ++i) {
      const int slot = w * 256 + i * 64 + l;
      const int row = slot >> 3, cs = slot & 7;
      const unsigned short* src =
          Xc + (size_t)(m0 + row) * KCAT + k0 + ((cs ^ (row & 7)) << 3);
      __builtin_amdgcn_global_load_lds(
          (const __attribute__((address_space(1))) void*)src,
          (__attribute__((address_space(3))) void*)&As[buf][(w * 256 + i * 64) * 8],
          16, 0, 0);
    }
#pragma unroll
    for (int i = 0; i < 2; ++i) {
      const int slot = w * 128 + i * 64 + l;
      const int row = slot >> 3, cs = slot & 7;
      const unsigned short* src =
          Wc + (size_t)(n0 + row) * KCAT + k0 + ((cs ^ (row & 7)) << 3);
      __builtin_amdgcn_global_load_lds(
          (const __attribute__((address_space(1))) void*)src,
          (__attribute__((address_space(3))) void*)&Bs[buf][(w * 128 + i * 64) * 8],
          16, 0, 0);
    }
  };

  stage(0, 0);
  __syncthreads();
  int cur = 0;
  for (int kt = 0; kt < KCAT / 64; ++kt) {
    if (kt < KCAT / 64 - 1) stage(cur ^ 1, (kt + 1) * 64);
    const unsigned short* __restrict__ Ab = As[cur];
    const unsigned short* __restrict__ Bb = Bs[cur];
#pragma unroll
    for (int s = 0; s < 2; ++s) {
      const int kc = s * 4 + (l >> 4);
      bf16x8 af[2], bfr[4];
#pragma unroll
      for (int fm = 0; fm < 2; ++fm) {
        const int row = w * 32 + fm * 16 + (l & 15);
        af[fm] = *(const bf16x8*)&Ab[row * 64 + ((kc ^ (row & 7)) << 3)];
      }
#pragma unroll
      for (int fn = 0; fn < 4; ++fn) {
        const int row = fn * 16 + (l & 15);
        bfr[fn] = *(const bf16x8*)&Bb[row * 64 + ((kc ^ (row & 7)) << 3)];
      }
#pragma unroll
      for (int fm = 0; fm < 2; ++fm)
#pragma unroll
        for (int fn = 0; fn < 4; ++fn)
          acc[fm][fn] = __builtin_amdgcn_mfma_f32_16x16x32_bf16(
              af[fm], bfr[fn], acc[fm][fn], 0, 0, 0);
    }
    __syncthreads();
    cur ^= 1;
  }

  const int h = n0 >> 6;
  const int col = l & 15, rb = (l >> 4) * 4;
#pragma unroll
  for (int fn = 0; fn < 4; ++fn) {
    const float bv = bias[n0 + fn * 16 + col];
#pragma unroll
    for (int fm = 0; fm < 2; ++fm) {
#pragma unroll
      for (int r = 0; r < 4; ++r) {
        const int m = m0 + w * 32 + fm * 16 + rb + r;
        const size_t oi = ((size_t)h * SEQ + m) * HD + fn * 16 + col;
        const float val = (acc[fm][fn][r] + bv) * scale;
        if (out) out[oi] = val;
        if (outb) outb[oi] = f2bf(val);
      }
    }
  }
}

// ---------------- shared-mem layouts for fused attention ----------------
struct LocalSmem {
  unsigned short qs[QR * 64];      // 4KB  swizzled Q
  unsigned short ks[2][64 * 64];   // 16KB double-buffered K / V^T chunks
  unsigned short pbf[QR * NSMAX];  // 20KB P bf16 swizzled
  int scol[NSMAX];
  int scm[NSMAX];
  int mrow[QR];
  float pmax[4][QR], psum[4][QR];
  float rmaxs[QR], rinvs[QR];
};
struct GlobSmem {
  float sc[SEQ];
  float qrow[HD];
  float red[8];
  float ctxp[4][HD];
};

__device__ inline float wave_max(float x) {
#pragma unroll
  for (int o = 32; o > 0; o >>= 1) x = fmaxf(x, __shfl_xor(x, o));
  return x;
}
__device__ inline float wave_sum(float x) {
#pragma unroll
  for (int o = 32; o > 0; o >>= 1) x += __shfl_xor(x, o);
  return x;
}

// --- fused attention: growrow(256) | global(256) | local(512, QR=32, dbuf) ---
__global__ __launch_bounds__(256) void attn_fused_kernel(
    const unsigned short* __restrict__ qb, const unsigned short* __restrict__ kb,
    const unsigned short* __restrict__ vb, const float* __restrict__ q,
    const float* __restrict__ kx, const float* __restrict__ qg,
    const float* __restrict__ kg, const float* __restrict__ vg,
    const int* __restrict__ mask, const int* __restrict__ g,
    float* __restrict__ out, float* __restrict__ attn) {
  __shared__ __align__(16) unsigned char smem_raw[
      sizeof(LocalSmem) > sizeof(GlobSmem) ? sizeof(LocalSmem) : sizeof(GlobSmem)];
  const int bid = blockIdx.x;
  const int t = threadIdx.x;

  if (bid >= 512) {
    // ===== LOCAL: 32 query rows/block, double-buffered chunk pipeline =======
    LocalSmem& S = *reinterpret_cast<LocalSmem*>(smem_raw);
    const int z = bid - 512;       // 512 blocks
    const int h = z & 7;           // head -> XCD
    const int r0 = (z >> 3) * QR;
    const int w = t >> 6, l = t & 63;
    const int g4 = l >> 4;
    const int lane15 = l & 15;

    const int nglob_raw = g[0];
    const int nglob = nglob_raw < 32 ? nglob_raw : 32;
    const int lo = (r0 - WIN) > 0 ? (r0 - WIN) : 0;
    const int hi = (r0 + QR - 1 + WIN) < (SEQ - 1) ? (r0 + QR - 1 + WIN) : (SEQ - 1);
    const int blen = hi - lo + 1;
    const int nslots = blen + nglob;

    if (t < QR) S.mrow[t] = mask[r0 + t];
    for (int j = t; j < NSMAX; j += 256) {
      int c = lo;
      if (j < blen) c = lo + j;
      else if (j < nslots) c = g[1 + j - blen];
      S.scol[j] = c;
      S.scm[j] = mask[c];
    }
    {  // Q stage: QR*8 = 256 16B chunks, one per thread
      const int row = t >> 3, ch = t & 7;
      *(int4*)&S.qs[row * 64 + ((ch ^ (row & 7)) << 3)] =
          *(const int4*)&qb[((size_t)h * SEQ + r0 + row) * HD + ch * 8];
    }
    __syncthreads();  // B1: scol/scm/mrow/qs ready

    auto stageK = [&](int buf, int c) {
#pragma unroll
      for (int l2 = 0; l2 < 2; ++l2) {
        const int idx = t + l2 * 256;
        const int sl = idx >> 3, ch = idx & 7;
        const int cc = S.scol[c * 64 + sl];
        *(int4*)&S.ks[buf][sl * 64 + ((ch ^ (sl & 7)) << 3)] =
            *(const int4*)&kb[((size_t)h * SEQ + cc) * HD + ch * 8];
      }
    };
    auto stageV = [&](int buf, int c) {
      const int sl = t & 63;
      const int cc = S.scol[c * 64 + sl];
      const unsigned short* vr = &vb[((size_t)h * SEQ + cc) * HD];
#pragma unroll
      for (int l2 = 0; l2 < 4; ++l2) {
        const int d4 = (t >> 6) + l2 * 4;
        const ushort4 vv = *(const ushort4*)&vr[d4 * 4];
#pragma unroll
        for (int e = 0; e < 4; ++e) {
          const int d = d4 * 4 + e;
          S.ks[buf][d * 64 + (((sl >> 3) ^ (d & 7)) << 3) + (sl & 7)] =
              ((const unsigned short*)&vv)[e];
        }
      }
    };

    // ---- score phase: dbuf pipeline, 1 barrier/chunk ----
    f32x4 acc[2][5];
#pragma unroll
    for (int rg = 0; rg < 2; ++rg)
#pragma unroll
      for (int c = 0; c < 5; ++c) acc[rg][c] = (f32x4)0.0f;

    stageK(0, 0);
    __syncthreads();
    const int slB = w * 16 + lane15;
#pragma unroll
    for (int c = 0; c < 5; ++c) {
      if (c < 4) stageK((c + 1) & 1, c + 1);
      const unsigned short* kbuf = S.ks[c & 1];
#pragma unroll
      for (int s = 0; s < 2; ++s) {
        const int kc = s * 4 + g4;
        const bf16x8 kf = *(const bf16x8*)&kbuf[slB * 64 + ((kc ^ (slB & 7)) << 3)];
#pragma unroll
        for (int rg = 0; rg < 2; ++rg) {
          const int arow = rg * 16 + lane15;
          const bf16x8 af =
              *(const bf16x8*)&S.qs[arow * 64 + ((kc ^ (arow & 7)) << 3)];
          acc[rg][c] =
              __builtin_amdgcn_mfma_f32_16x16x32_bf16(af, kf, acc[rg][c], 0, 0, 0);
        }
      }
      __syncthreads();
    }

    // ---- mask + row max ----
    float pmx[2][4];
#pragma unroll
    for (int rg = 0; rg < 2; ++rg)
#pragma unroll
      for (int r = 0; r < 4; ++r) pmx[rg][r] = -3e30f;
#pragma unroll
    for (int c = 0; c < 5; ++c) {
      const int n = 64 * c + 16 * w + lane15;
      const int cc = S.scol[n], mc = S.scm[n];
      const bool gl = (n >= blen);
#pragma unroll
      for (int rg = 0; rg < 2; ++rg)
#pragma unroll
        for (int r = 0; r < 4; ++r) {
          const int m = r0 + rg * 16 + g4 * 4 + r;
          bool ok;
          if (!gl) {
            const int dist = m > cc ? m - cc : cc - m;
            ok = (mc != 0) && (dist <= WIN || mc == -1);
          } else {
            ok = (n < nslots) && (cc < lo || cc > hi);
          }
          const float s = ok ? acc[rg][c][r] : -1e30f;
          acc[rg][c][r] = s;
          pmx[rg][r] = fmaxf(pmx[rg][r], s);
        }
    }
#pragma unroll
    for (int off = 1; off < 16; off <<= 1)
#pragma unroll
      for (int rg = 0; rg < 2; ++rg)
#pragma unroll
        for (int r = 0; r < 4; ++r)
          pmx[rg][r] = fmaxf(pmx[rg][r], __shfl_xor(pmx[rg][r], off));
    if (lane15 == 0)
#pragma unroll
      for (int rg = 0; rg < 2; ++rg)
#pragma unroll
        for (int r = 0; r < 4; ++r)
          S.pmax[w][rg * 16 + g4 * 4 + r] = pmx[rg][r];
    __syncthreads();  // B2
    if (t < QR)
      S.rmaxs[t] = fmaxf(fmaxf(S.pmax[0][t], S.pmax[1][t]),
                         fmaxf(S.pmax[2][t], S.pmax[3][t]));
    __syncthreads();  // B3

    // ---- exp + row sum + P->bf16 LDS ----
    float rmx[2][4], psm[2][4];
#pragma unroll
    for (int rg = 0; rg < 2; ++rg)
#pragma unroll
      for (int r = 0; r < 4; ++r) {
        rmx[rg][r] = S.rmaxs[rg * 16 + g4 * 4 + r];
        psm[rg][r] = 0.f;
      }
#pragma unroll
    for (int c = 0; c < 5; ++c)
#pragma unroll
      for (int rg = 0; rg < 2; ++rg)
#pragma unroll
        for (int r = 0; r < 4; ++r) {
          const float s = acc[rg][c][r];
          const float p = (s > -1e29f) ? __expf(s - rmx[rg][r]) : 0.0f;
          acc[rg][c][r] = p;
          psm[rg][r] += p;
        }
#pragma unroll
    for (int off = 1; off < 16; off <<= 1)
#pragma unroll
      for (int rg = 0; rg < 2; ++rg)
#pragma unroll
        for (int r = 0; r < 4; ++r) psm[rg][r] += __shfl_xor(psm[rg][r], off);
    if (lane15 == 0)
#pragma unroll
      for (int rg = 0; rg < 2; ++rg)
#pragma unroll
        for (int r = 0; r < 4; ++r)
          S.psum[w][rg * 16 + g4 * 4 + r] = psm[rg][r];
#pragma unroll
    for (int c = 0; c < 5; ++c) {
      const int n = 64 * c + 16 * w + lane15;
#pragma unroll
      for (int rg = 0; rg < 2; ++rg)
#pragma unroll
        for (int r = 0; r < 4; ++r) {
          const int m = rg * 16 + g4 * 4 + r;
          S.pbf[m * NSMAX + (((n >> 3) ^ (m & 7)) << 3) + (n & 7)] =
              f2bf(acc[rg][c][r]);
        }
    }
    __syncthreads();  // B4
    if (t < QR)
      S.rinvs[t] = 1.0f / (S.psum[0][t] + S.psum[1][t] + S.psum[2][t] + S.psum[3][t]);
    __syncthreads();  // B5

    // ---- p-stores (zeros pre-filled); V chunk0 stage overlaps them ----
    stageV(0, 0);
#pragma unroll
    for (int c = 0; c < 5; ++c) {
      const int n = 64 * c + 16 * w + lane15;
      const int cc = S.scol[n];
      const bool gl = (n >= blen);
      const bool gok = gl && (n < nslots) && (cc < lo || cc > hi);
#pragma unroll
      for (int rg = 0; rg < 2; ++rg)
#pragma unroll
        for (int r = 0; r < 4; ++r) {
          const int m = rg * 16 + g4 * 4 + r;
          const float pp = acc[rg][c][r];
          if (S.mrow[m] == 1 && (!gl || gok) && pp != 0.0f)
            attn[(size_t)h * SEQ * SEQ + (size_t)(r0 + m) * SEQ + cc] =
                pp * S.rinvs[m];
        }
    }
    __syncthreads();  // drains stageV(0)

    // ---- PV phase: dbuf pipeline ----
    f32x4 cacc[2];
    cacc[0] = (f32x4)0.0f;
    cacc[1] = (f32x4)0.0f;
    const int dB = w * 16 + lane15;
#pragma unroll
    for (int c = 0; c < 5; ++c) {
      if (c < 4) stageV((c + 1) & 1, c + 1);
      const unsigned short* vbuf = S.ks[c & 1];
#pragma unroll
      for (int s = 0; s < 2; ++s) {
        const int pc = c * 8 + s * 4 + g4;
        const int kc = s * 4 + g4;
        const bf16x8 bfv =
            *(const bf16x8*)&vbuf[dB * 64 + ((kc ^ (dB & 7)) << 3)];
#pragma unroll
        for (int rg = 0; rg < 2; ++rg) {
          const int arow = rg * 16 + lane15;
          const bf16x8 af =
              *(const bf16x8*)&S.pbf[arow * NSMAX + ((pc ^ (arow & 7)) << 3)];
          cacc[rg] =
              __builtin_amdgcn_mfma_f32_16x16x32_bf16(af, bfv, cacc[rg], 0, 0, 0);
        }
      }
      __syncthreads();
    }

    // ---- out epilogue (skip mi==-1: global path owns those rows) ----
#pragma unroll
    for (int rg = 0; rg < 2; ++rg)
#pragma unroll
      for (int r = 0; r < 4; ++r) {
        const int m = rg * 16 + g4 * 4 + r;
        const int mi = S.mrow[m];
        if (mi != -1) {
          const float val = (mi == 0) ? 0.f : cacc[rg][r] * S.rinvs[m];
          out[(size_t)(r0 + m) * DIM + h * HD + dB] = val;
        }
      }
    return;
  }

  GlobSmem& S = *reinterpret_cast<GlobSmem*>(smem_raw);
  const int nglob = g[0];

  if (bid < 256) {
    // ============ GROWROW: local-attn probs for mi==-1 rows (whole row) ======
    const int b = bid;
    const int j0 = b >> 3;
    const int h = b & 7;

    for (int jj = j0; jj < nglob; jj += 32) {
      const int i = g[1 + jj];
      __syncthreads();
      if (t < HD) S.qrow[t] = q[((size_t)h * SEQ + i) * HD + t];
      __syncthreads();

      float lmax = -1e30f;
#pragma unroll 2
      for (int c = t; c < SEQ; c += 256) {
        const bool ok = (mask[c] != 0);
        const float* kr = &kx[((size_t)h * SEQ + c) * HD];
        float a0 = 0.f, a1 = 0.f, a2 = 0.f, a3 = 0.f;
#pragma unroll
        for (int d = 0; d < HD; d += 4) {
          const float4 kv = *(const float4*)&kr[d];
          const float4 qv = *(const float4*)&S.qrow[d];
          a0 = fmaf(qv.x, kv.x, a0);
          a1 = fmaf(qv.y, kv.y, a1);
          a2 = fmaf(qv.z, kv.z, a2);
          a3 = fmaf(qv.w, kv.w, a3);
        }
        const float s = ok ? ((a0 + a1) + (a2 + a3)) : -1e30f;
        lmax = fmaxf(lmax, s);
        S.sc[c] = s;
      }
      const float wm = wave_max(lmax);
      if ((t & 63) == 0) S.red[t >> 6] = wm;
      __syncthreads();
      const float rmax = fmaxf(fmaxf(S.red[0], S.red[1]), fmaxf(S.red[2], S.red[3]));

      float lsum = 0.f;
#pragma unroll 2
      for (int c = t; c < SEQ; c += 256) {
        const float s = S.sc[c];
        const float pp = (s > -1e29f) ? __expf(s - rmax) : 0.0f;
        S.sc[c] = pp;
        lsum += pp;
      }
      const float wsum = wave_sum(lsum);
      __syncthreads();
      if ((t & 63) == 0) S.red[4 + (t >> 6)] = wsum;
      __syncthreads();
      const float rsum = (S.red[4] + S.red[5]) + (S.red[6] + S.red[7]);
      const float inv = 1.0f / rsum;

      float* __restrict__ arow = attn + (size_t)h * SEQ * SEQ + (size_t)i * SEQ;
      __syncthreads();
      for (int c4 = t; c4 < 512; c4 += 256) {
        f32x4 pv;
        pv[0] = S.sc[c4 * 4 + 0] * inv;
        pv[1] = S.sc[c4 * 4 + 1] * inv;
        pv[2] = S.sc[c4 * 4 + 2] * inv;
        pv[3] = S.sc[c4 * 4 + 3] * inv;
        *(f32x4*)&arow[c4 * 4] = pv;
      }
    }
    return;
  }

  // ============ GLOBAL branch: out rows for mi==-1 ============
  {
    const int b = bid - 256;
    const int j0 = b >> 3;
    const int h = b & 7;

    for (int jj = j0; jj < nglob; jj += 32) {
      const int i = g[1 + jj];
      __syncthreads();
      if (t < HD) S.qrow[t] = qg[((size_t)h * SEQ + i) * HD + t];
      __syncthreads();

      float lmax = -1e30f;
#pragma unroll 2
      for (int c = t; c < SEQ; c += 256) {
        const bool ok = (mask[c] != 0);
        const float* kr = &kg[((size_t)h * SEQ + c) * HD];
        float a0 = 0.f, a1 = 0.f, a2 = 0.f, a3 = 0.f;
#pragma unroll
        for (int d = 0; d < HD; d += 4) {
          const float4 kv = *(const float4*)&kr[d];
          const float4 qv = *(const float4*)&S.qrow[d];
          a0 = fmaf(qv.x, kv.x, a0);
          a1 = fmaf(qv.y, kv.y, a1);
          a2 = fmaf(qv.z, kv.z, a2);
          a3 = fmaf(qv.w, kv.w, a3);
        }
        const float s = ok ? ((a0 + a1) + (a2 + a3)) : -1e30f;
        lmax = fmaxf(lmax, s);
        S.sc[c] = s;
      }
      const float wm = wave_max(lmax);
      if ((t & 63) == 0) S.red[t >> 6] = wm;
      __syncthreads();
      const float rmax = fmaxf(fmaxf(S.red[0], S.red[1]), fmaxf(S.red[2], S.red[3]));

      float lsum = 0.f;
#pragma unroll 2
      for (int c = t; c < SEQ; c += 256) {
        const float s = S.sc[c];
        const float pp = (s > -1e29f) ? __expf(s - rmax) : 0.0f;
        S.sc[c] = pp;
        lsum += pp;
      }
      const float wsum = wave_sum(lsum);
      __syncthreads();
      if ((t & 63) == 0) S.red[4 + (t >> 6)] = wsum;
      __syncthreads();
      const float rsum = (S.red[4] + S.red[5]) + (S.red[6] + S.red[7]);
      const float inv = 1.0f / rsum;

      const int wv = t >> 6;
      const int d = t & 63;
      float ctx = 0.f;
#pragma unroll 8
      for (int c = wv; c < SEQ; c += 4) {
        ctx = fmaf(S.sc[c], vg[((size_t)h * SEQ + c) * HD + d], ctx);
      }
      S.ctxp[wv][d] = ctx;
      __syncthreads();
      if (t < HD) {
        const float r =
            ((S.ctxp[0][t] + S.ctxp[1][t]) + (S.ctxp[2][t] + S.ctxp[3][t])) * inv;
        out[(size_t)i * DIM + h * HD + t] = r;
      }
    }
  }
}

// ---------------- host ----------------
extern "C" void kernel_launch(void* const* d_in, const int* in_sizes, int n_in,
                              void* d_out, int out_size, void* d_ws, size_t ws_size,
                              hipStream_t stream) {
  const float* hs = (const float*)d_in[0];
  const int* mask = (const int*)d_in[13];

  float* q  = (float*)d_ws;                      // 6 x 4MB fp32 projections
  float* kx = q  + (size_t)SEQ * DIM;
  float* vx = kx + (size_t)SEQ * DIM;            // (vx fp32 unused; slot kept)
  float* qg = vx + (size_t)SEQ * DIM;
  float* kg = qg + (size_t)SEQ * DIM;
  float* vg = kg + (size_t)SEQ * DIM;
  int* gcols = (int*)(vg + (size_t)SEQ * DIM);   // 16KB reserved
  unsigned short* Xcat = (unsigned short*)((char*)gcols + 16384);  // 6MB
  unsigned short* Wcat0 = Xcat + (size_t)SEQ * KCAT;               // 9MB
  unsigned short* qbb = Wcat0 + (size_t)6 * DIM * KCAT;            // 3 x 2MB bf16
  unsigned short* kbb = qbb + (size_t)SEQ * DIM;
  unsigned short* vbb = kbb + (size_t)SEQ * DIM;

  float* out  = (float*)d_out;            // [1,S,DIM]
  float* attn = out + (size_t)SEQ * DIM;  // [1,H,S,S]

  hipLaunchKernelGGL(fill_attn_kernel, dim3(1024), dim3(256), 0, stream, attn);

  WArgs wa;
  PMArgs pm;
  float* pouts[6] = {q, kx, nullptr, qg, kg, vg};  // vx fp32 dead -> skip
  unsigned short* poutb[6] = {qbb, kbb, vbb, nullptr, nullptr, nullptr};
  for (int p = 0; p < 6; ++p) {
    wa.W[p] = (const float*)d_in[1 + 2 * p];
    wa.Wc[p] = Wcat0 + (size_t)p * DIM * KCAT;
    pm.Wc[p] = wa.Wc[p];
    pm.b[p] = (const float*)d_in[2 + 2 * p];
    pm.out[p] = pouts[p];
    pm.outb[p] = poutb[p];
  }

  hipLaunchKernelGGL(prep_kernel, dim3(2561), dim3(256), 0, stream, hs, Xcat, wa,
                     mask, gcols);

  dim3 g1(SEQ / 128, DIM / 64, 6);
  hipLaunchKernelGGL(proj_mfma_kernel, g1, dim3(256), 0, stream, Xcat, pm);

  hipLaunchKernelGGL(attn_fused_kernel, dim3(1024), dim3(256), 0, stream, qbb, kbb,
                     vbb, q, kx, qg, kg, vg, mask, gcols, out, attn);
}

// Round 20
// 107.622 us; speedup vs baseline: 1.0797x; 1.0797x over previous
//
#include <hip/hip_runtime.h>

#define SEQ 2048
#define DIM 512
#define HEADS 8
#define HD 64
#define WIN 128
#define NSMAX 320  // 288 band-union + up to 32 global cols
#define KCAT 1536  // 3x bf16-split K
#define QR 32      // query rows per local-attn block

typedef short bf16x8 __attribute__((ext_vector_type(8)));
typedef float f32x4 __attribute__((ext_vector_type(4)));

__device__ inline unsigned short f2bf(float x) {
  unsigned u = __float_as_uint(x);
  unsigned r = (u + 0x7FFF + ((u >> 16) & 1)) >> 16;  // RTNE
  return (unsigned short)r;
}
__device__ inline float bf2f(unsigned short s) {
  return __uint_as_float((unsigned)s << 16);
}

__device__ inline void fill_tile(float* __restrict__ attn, int tile, int t) {
  // one tile = 16384 floats = 64 KB, coalesced f32x4 stores
  float* dst = attn + (size_t)tile * 16384;
  const f32x4 z4 = (f32x4)0.0f;
#pragma unroll
  for (int i = 0; i < 16; ++i) *(f32x4*)&dst[(i * 256 + t) * 4] = z4;
}

struct WArgs { const float* W[6]; unsigned short* Wc[6]; };

// ---- prep: fill tiles 0-1023 | convert_x | convert_w | setup ----------------
__global__ __launch_bounds__(256) void prep_kernel(
    const float* __restrict__ X, unsigned short* __restrict__ Xc, WArgs a,
    const int* __restrict__ mask, int* __restrict__ g,
    float* __restrict__ attn) {
  const int bid = blockIdx.x;
  const int t = threadIdx.x;

  if (bid < 1024) {  // first half of the attn zero-fill (67 MB)
    fill_tile(attn, bid, t);
    return;
  }
  if (bid < 2048) {  // convert X -> Xcat = [hi | hi | lo]
    const int idx = ((bid - 1024) * 256 + t) * 4;
    const int m = idx >> 9, k = idx & 511;
    const float4 xv = *(const float4*)&X[idx];
    ushort4 hi, lo;
    hi.x = f2bf(xv.x); lo.x = f2bf(xv.x - bf2f(hi.x));
    hi.y = f2bf(xv.y); lo.y = f2bf(xv.y - bf2f(hi.y));
    hi.z = f2bf(xv.z); lo.z = f2bf(xv.z - bf2f(hi.z));
    hi.w = f2bf(xv.w); lo.w = f2bf(xv.w - bf2f(hi.w));
    unsigned short* row = Xc + (size_t)m * KCAT;
    *(ushort4*)&row[k] = hi;
    *(ushort4*)&row[k + 512] = hi;
    *(ushort4*)&row[k + 1024] = lo;
    return;
  }
  if (bid < 3584) {  // convert W_p -> Wcat_p = [hi | lo | hi]
    const int b = bid - 2048;
    const int p = b >> 8;
    const float* __restrict__ W = a.W[p];
    unsigned short* __restrict__ Wc = a.Wc[p];
    const int idx = ((b & 255) * 256 + t) * 4;
    const float4 xv = *(const float4*)&W[idx];
    ushort4 hi, lo;
    hi.x = f2bf(xv.x); lo.x = f2bf(xv.x - bf2f(hi.x));
    hi.y = f2bf(xv.y); lo.y = f2bf(xv.y - bf2f(hi.y));
    hi.z = f2bf(xv.z); lo.z = f2bf(xv.z - bf2f(hi.z));
    hi.w = f2bf(xv.w); lo.w = f2bf(xv.w - bf2f(hi.w));
    unsigned short* row = Wc + (size_t)(idx >> 9) * KCAT;
    const int k = idx & 511;
    *(ushort4*)&row[k] = hi;
    *(ushort4*)&row[k + 512] = lo;
    *(ushort4*)&row[k + 1024] = hi;
    return;
  }
  // setup: ordered compact list of global columns
  {
    __shared__ int wtot[4];
    const int lane = t & 63;
    const int wv = t >> 6;
    int loc[8];
    int n = 0;
    const int base = t * 8;
#pragma unroll
    for (int j = 0; j < 8; ++j) {
      const int c = base + j;
      if (mask[c] == -1) loc[n++] = c;
    }
    int x = n;
#pragma unroll
    for (int o = 1; o < 64; o <<= 1) {
      const int y = __shfl_up(x, o);
      if (lane >= o) x += y;
    }
    if (lane == 63) wtot[wv] = x;
    __syncthreads();
    int basew = 0;
    for (int w = 0; w < wv; ++w) basew += wtot[w];
    if (t == 255) g[0] = basew + x;
    const int off = basew + x - n;
    for (int j = 0; j < n; ++j) g[1 + off + j] = loc[j];
  }
}

// ---------------- MFMA projection GEMM + fill plane (z==6) -------------------
struct PMArgs {
  const unsigned short* Wc[6];
  const float* b[6];
  float* out[6];             // fp32 outputs (null = skip)
  unsigned short* outb[6];   // bf16 copies (q,k,v only; else null)
};
__global__ __launch_bounds__(256) void proj_mfma_kernel(
    const unsigned short* __restrict__ Xc, PMArgs a, float* __restrict__ attn) {
  const int p = blockIdx.z;
  const int t = threadIdx.x;

  if (p == 6) {  // second half of the attn zero-fill (67 MB), overlaps GEMM
    const int idx = blockIdx.y * 16 + blockIdx.x;  // 128 blocks
#pragma unroll
    for (int i = 0; i < 8; ++i) fill_tile(attn, 1024 + idx * 8 + i, t);
    return;
  }

  const unsigned short* __restrict__ Wc = a.Wc[p];
  const float* __restrict__ bias = a.b[p];
  float* __restrict__ out = a.out[p];
  unsigned short* __restrict__ outb = a.outb[p];
  const float scale = (p == 0 || p == 3) ? 0.125f : 1.0f;

  __shared__ __align__(16) unsigned short As[2][128 * 64];  // 2 x 16KB
  __shared__ __align__(16) unsigned short Bs[2][64 * 64];   // 2 x 8KB

  const int w = t >> 6, l = t & 63;
  const int m0 = blockIdx.x * 128, n0 = blockIdx.y * 64;

  f32x4 acc[2][4];
#pragma unroll
  for (int i = 0; i < 2; ++i)
#pragma unroll
    for (int j = 0; j < 4; ++j) acc[i][j] = (f32x4)0.0f;

  auto stage = [&](int buf, int k0) {
#pragma unroll
    for (int i = 0; i < 4; ++i) {
      const int slot = w * 256 + i * 64 + l;
      const int row = slot >> 3, cs = slot & 7;
      const unsigned short* src =
          Xc + (size_t)(m0 + row) * KCAT + k0 + ((cs ^ (row & 7)) << 3);
      __builtin_amdgcn_global_load_lds(
          (const __attribute__((address_space(1))) void*)src,
          (__attribute__((address_space(3))) void*)&As[buf][(w * 256 + i * 64) * 8],
          16, 0, 0);
    }
#pragma unroll
    for (int i = 0; i < 2; ++i) {
      const int slot = w * 128 + i * 64 + l;
      const int row = slot >> 3, cs = slot & 7;
      const unsigned short* src =
          Wc + (size_t)(n0 + row) * KCAT + k0 + ((cs ^ (row & 7)) << 3);
      __builtin_amdgcn_global_load_lds(
          (const __attribute__((address_space(1))) void*)src,
          (__attribute__((address_space(3))) void*)&Bs[buf][(w * 128 + i * 64) * 8],
          16, 0, 0);
    }
  };

  stage(0, 0);
  __syncthreads();
  int cur = 0;
  for (int kt = 0; kt < KCAT / 64; ++kt) {
    if (kt < KCAT / 64 - 1) stage(cur ^ 1, (kt + 1) * 64);
    const unsigned short* __restrict__ Ab = As[cur];
    const unsigned short* __restrict__ Bb = Bs[cur];
#pragma unroll
    for (int s = 0; s < 2; ++s) {
      const int kc = s * 4 + (l >> 4);
      bf16x8 af[2], bfr[4];
#pragma unroll
      for (int fm = 0; fm < 2; ++fm) {
        const int row = w * 32 + fm * 16 + (l & 15);
        af[fm] = *(const bf16x8*)&Ab[row * 64 + ((kc ^ (row & 7)) << 3)];
      }
#pragma unroll
      for (int fn = 0; fn < 4; ++fn) {
        const int row = fn * 16 + (l & 15);
        bfr[fn] = *(const bf16x8*)&Bb[row * 64 + ((kc ^ (row & 7)) << 3)];
      }
#pragma unroll
      for (int fm = 0; fm < 2; ++fm)
#pragma unroll
        for (int fn = 0; fn < 4; ++fn)
          acc[fm][fn] = __builtin_amdgcn_mfma_f32_16x16x32_bf16(
              af[fm], bfr[fn], acc[fm][fn], 0, 0, 0);
    }
    __syncthreads();
    cur ^= 1;
  }

  const int h = n0 >> 6;
  const int col = l & 15, rb = (l >> 4) * 4;
#pragma unroll
  for (int fn = 0; fn < 4; ++fn) {
    const float bv = bias[n0 + fn * 16 + col];
#pragma unroll
    for (int fm = 0; fm < 2; ++fm) {
#pragma unroll
      for (int r = 0; r < 4; ++r) {
        const int m = m0 + w * 32 + fm * 16 + rb + r;
        const size_t oi = ((size_t)h * SEQ + m) * HD + fn * 16 + col;
        const float val = (acc[fm][fn][r] + bv) * scale;
        if (out) out[oi] = val;
        if (outb) outb[oi] = f2bf(val);
      }
    }
  }
}

// ---------------- shared-mem layouts for fused attention ----------------
struct LocalSmem {
  unsigned short qs[QR * 64];      // 4KB  swizzled Q
  unsigned short ks[2][64 * 64];   // 16KB double-buffered K / V^T chunks
  unsigned short pbf[QR * NSMAX];  // 20KB P bf16 swizzled
  int scol[NSMAX];
  int scm[NSMAX];
  int mrow[QR];
  float pmax[4][QR], psum[4][QR];
  float rmaxs[QR], rinvs[QR];
};
struct GlobSmem {
  float sc[SEQ];
  float qrow[HD];
  float red[8];
  float ctxp[4][HD];
};

__device__ inline float wave_max(float x) {
#pragma unroll
  for (int o = 32; o > 0; o >>= 1) x = fmaxf(x, __shfl_xor(x, o));
  return x;
}
__device__ inline float wave_sum(float x) {
#pragma unroll
  for (int o = 32; o > 0; o >>= 1) x += __shfl_xor(x, o);
  return x;
}

// --- fused attention: growrow(256) | global(256) | local(512, QR=32, dbuf) ---
__global__ __launch_bounds__(256) void attn_fused_kernel(
    const unsigned short* __restrict__ qb, const unsigned short* __restrict__ kb,
    const unsigned short* __restrict__ vb, const float* __restrict__ q,
    const float* __restrict__ kx, const float* __restrict__ qg,
    const float* __restrict__ kg, const float* __restrict__ vg,
    const int* __restrict__ mask, const int* __restrict__ g,
    float* __restrict__ out, float* __restrict__ attn) {
  __shared__ __align__(16) unsigned char smem_raw[
      sizeof(LocalSmem) > sizeof(GlobSmem) ? sizeof(LocalSmem) : sizeof(GlobSmem)];
  const int bid = blockIdx.x;
  const int t = threadIdx.x;

  if (bid >= 512) {
    // ===== LOCAL: 32 query rows/block, double-buffered chunk pipeline =======
    LocalSmem& S = *reinterpret_cast<LocalSmem*>(smem_raw);
    const int z = bid - 512;       // 512 blocks
    const int h = z & 7;           // head -> XCD
    const int r0 = (z >> 3) * QR;
    const int w = t >> 6, l = t & 63;
    const int g4 = l >> 4;
    const int lane15 = l & 15;

    const int nglob_raw = g[0];
    const int nglob = nglob_raw < 32 ? nglob_raw : 32;
    const int lo = (r0 - WIN) > 0 ? (r0 - WIN) : 0;
    const int hi = (r0 + QR - 1 + WIN) < (SEQ - 1) ? (r0 + QR - 1 + WIN) : (SEQ - 1);
    const int blen = hi - lo + 1;
    const int nslots = blen + nglob;

    if (t < QR) S.mrow[t] = mask[r0 + t];
    for (int j = t; j < NSMAX; j += 256) {
      int c = lo;
      if (j < blen) c = lo + j;
      else if (j < nslots) c = g[1 + j - blen];
      S.scol[j] = c;
      S.scm[j] = mask[c];
    }
    {  // Q stage: QR*8 = 256 16B chunks, one per thread
      const int row = t >> 3, ch = t & 7;
      *(int4*)&S.qs[row * 64 + ((ch ^ (row & 7)) << 3)] =
          *(const int4*)&qb[((size_t)h * SEQ + r0 + row) * HD + ch * 8];
    }
    __syncthreads();  // B1: scol/scm/mrow/qs ready

    auto stageK = [&](int buf, int c) {
#pragma unroll
      for (int l2 = 0; l2 < 2; ++l2) {
        const int idx = t + l2 * 256;
        const int sl = idx >> 3, ch = idx & 7;
        const int cc = S.scol[c * 64 + sl];
        *(int4*)&S.ks[buf][sl * 64 + ((ch ^ (sl & 7)) << 3)] =
            *(const int4*)&kb[((size_t)h * SEQ + cc) * HD + ch * 8];
      }
    };
    auto stageV = [&](int buf, int c) {
      const int sl = t & 63;
      const int cc = S.scol[c * 64 + sl];
      const unsigned short* vr = &vb[((size_t)h * SEQ + cc) * HD];
#pragma unroll
      for (int l2 = 0; l2 < 4; ++l2) {
        const int d4 = (t >> 6) + l2 * 4;
        const ushort4 vv = *(const ushort4*)&vr[d4 * 4];
#pragma unroll
        for (int e = 0; e < 4; ++e) {
          const int d = d4 * 4 + e;
          S.ks[buf][d * 64 + (((sl >> 3) ^ (d & 7)) << 3) + (sl & 7)] =
              ((const unsigned short*)&vv)[e];
        }
      }
    };

    // ---- score phase: dbuf pipeline, 1 barrier/chunk ----
    f32x4 acc[2][5];
#pragma unroll
    for (int rg = 0; rg < 2; ++rg)
#pragma unroll
      for (int c = 0; c < 5; ++c) acc[rg][c] = (f32x4)0.0f;

    stageK(0, 0);
    __syncthreads();
    const int slB = w * 16 + lane15;
#pragma unroll
    for (int c = 0; c < 5; ++c) {
      if (c < 4) stageK((c + 1) & 1, c + 1);
      const unsigned short* kbuf = S.ks[c & 1];
#pragma unroll
      for (int s = 0; s < 2; ++s) {
        const int kc = s * 4 + g4;
        const bf16x8 kf = *(const bf16x8*)&kbuf[slB * 64 + ((kc ^ (slB & 7)) << 3)];
#pragma unroll
        for (int rg = 0; rg < 2; ++rg) {
          const int arow = rg * 16 + lane15;
          const bf16x8 af =
              *(const bf16x8*)&S.qs[arow * 64 + ((kc ^ (arow & 7)) << 3)];
          acc[rg][c] =
              __builtin_amdgcn_mfma_f32_16x16x32_bf16(af, kf, acc[rg][c], 0, 0, 0);
        }
      }
      __syncthreads();
    }

    // ---- mask + row max ----
    float pmx[2][4];
#pragma unroll
    for (int rg = 0; rg < 2; ++rg)
#pragma unroll
      for (int r = 0; r < 4; ++r) pmx[rg][r] = -3e30f;
#pragma unroll
    for (int c = 0; c < 5; ++c) {
      const int n = 64 * c + 16 * w + lane15;
      const int cc = S.scol[n], mc = S.scm[n];
      const bool gl = (n >= blen);
#pragma unroll
      for (int rg = 0; rg < 2; ++rg)
#pragma unroll
        for (int r = 0; r < 4; ++r) {
          const int m = r0 + rg * 16 + g4 * 4 + r;
          bool ok;
          if (!gl) {
            const int dist = m > cc ? m - cc : cc - m;
            ok = (mc != 0) && (dist <= WIN || mc == -1);
          } else {
            ok = (n < nslots) && (cc < lo || cc > hi);
          }
          const float s = ok ? acc[rg][c][r] : -1e30f;
          acc[rg][c][r] = s;
          pmx[rg][r] = fmaxf(pmx[rg][r], s);
        }
    }
#pragma unroll
    for (int off = 1; off < 16; off <<= 1)
#pragma unroll
      for (int rg = 0; rg < 2; ++rg)
#pragma unroll
        for (int r = 0; r < 4; ++r)
          pmx[rg][r] = fmaxf(pmx[rg][r], __shfl_xor(pmx[rg][r], off));
    if (lane15 == 0)
#pragma unroll
      for (int rg = 0; rg < 2; ++rg)
#pragma unroll
        for (int r = 0; r < 4; ++r)
          S.pmax[w][rg * 16 + g4 * 4 + r] = pmx[rg][r];
    __syncthreads();  // B2
    if (t < QR)
      S.rmaxs[t] = fmaxf(fmaxf(S.pmax[0][t], S.pmax[1][t]),
                         fmaxf(S.pmax[2][t], S.pmax[3][t]));
    __syncthreads();  // B3

    // ---- exp + row sum + P->bf16 LDS ----
    float rmx[2][4], psm[2][4];
#pragma unroll
    for (int rg = 0; rg < 2; ++rg)
#pragma unroll
      for (int r = 0; r < 4; ++r) {
        rmx[rg][r] = S.rmaxs[rg * 16 + g4 * 4 + r];
        psm[rg][r] = 0.f;
      }
#pragma unroll
    for (int c = 0; c < 5; ++c)
#pragma unroll
      for (int rg = 0; rg < 2; ++rg)
#pragma unroll
        for (int r = 0; r < 4; ++r) {
          const float s = acc[rg][c][r];
          const float p = (s > -1e29f) ? __expf(s - rmx[rg][r]) : 0.0f;
          acc[rg][c][r] = p;
          psm[rg][r] += p;
        }
#pragma unroll
    for (int off = 1; off < 16; off <<= 1)
#pragma unroll
      for (int rg = 0; rg < 2; ++rg)
#pragma unroll
        for (int r = 0; r < 4; ++r) psm[rg][r] += __shfl_xor(psm[rg][r], off);
    if (lane15 == 0)
#pragma unroll
      for (int rg = 0; rg < 2; ++rg)
#pragma unroll
        for (int r = 0; r < 4; ++r)
          S.psum[w][rg * 16 + g4 * 4 + r] = psm[rg][r];
#pragma unroll
    for (int c = 0; c < 5; ++c) {
      const int n = 64 * c + 16 * w + lane15;
#pragma unroll
      for (int rg = 0; rg < 2; ++rg)
#pragma unroll
        for (int r = 0; r < 4; ++r) {
          const int m = rg * 16 + g4 * 4 + r;
          S.pbf[m * NSMAX + (((n >> 3) ^ (m & 7)) << 3) + (n & 7)] =
              f2bf(acc[rg][c][r]);
        }
    }
    __syncthreads();  // B4
    if (t < QR)
      S.rinvs[t] = 1.0f / (S.psum[0][t] + S.psum[1][t] + S.psum[2][t] + S.psum[3][t]);
    __syncthreads();  // B5

    // ---- p-stores (zeros pre-filled); V chunk0 stage overlaps them ----
    stageV(0, 0);
#pragma unroll
    for (int c = 0; c < 5; ++c) {
      const int n = 64 * c + 16 * w + lane15;
      const int cc = S.scol[n];
      const bool gl = (n >= blen);
      const bool gok = gl && (n < nslots) && (cc < lo || cc > hi);
#pragma unroll
      for (int rg = 0; rg < 2; ++rg)
#pragma unroll
        for (int r = 0; r < 4; ++r) {
          const int m = rg * 16 + g4 * 4 + r;
          const float pp = acc[rg][c][r];
          if (S.mrow[m] == 1 && (!gl || gok) && pp != 0.0f)
            attn[(size_t)h * SEQ * SEQ + (size_t)(r0 + m) * SEQ + cc] =
                pp * S.rinvs[m];
        }
    }
    __syncthreads();  // drains stageV(0)

    // ---- PV phase: dbuf pipeline ----
    f32x4 cacc[2];
    cacc[0] = (f32x4)0.0f;
    cacc[1] = (f32x4)0.0f;
    const int dB = w * 16 + lane15;
#pragma unroll
    for (int c = 0; c < 5; ++c) {
      if (c < 4) stageV((c + 1) & 1, c + 1);
      const unsigned short* vbuf = S.ks[c & 1];
#pragma unroll
      for (int s = 0; s < 2; ++s) {
        const int pc = c * 8 + s * 4 + g4;
        const int kc = s * 4 + g4;
        const bf16x8 bfv =
            *(const bf16x8*)&vbuf[dB * 64 + ((kc ^ (dB & 7)) << 3)];
#pragma unroll
        for (int rg = 0; rg < 2; ++rg) {
          const int arow = rg * 16 + lane15;
          const bf16x8 af =
              *(const bf16x8*)&S.pbf[arow * NSMAX + ((pc ^ (arow & 7)) << 3)];
          cacc[rg] =
              __builtin_amdgcn_mfma_f32_16x16x32_bf16(af, bfv, cacc[rg], 0, 0, 0);
        }
      }
      __syncthreads();
    }

    // ---- out epilogue (skip mi==-1: global path owns those rows) ----
#pragma unroll
    for (int rg = 0; rg < 2; ++rg)
#pragma unroll
      for (int r = 0; r < 4; ++r) {
        const int m = rg * 16 + g4 * 4 + r;
        const int mi = S.mrow[m];
        if (mi != -1) {
          const float val = (mi == 0) ? 0.f : cacc[rg][r] * S.rinvs[m];
          out[(size_t)(r0 + m) * DIM + h * HD + dB] = val;
        }
      }
    return;
  }

  GlobSmem& S = *reinterpret_cast<GlobSmem*>(smem_raw);
  const int nglob = g[0];

  if (bid < 256) {
    // ============ GROWROW: local-attn probs for mi==-1 rows (whole row) ======
    const int b = bid;
    const int j0 = b >> 3;
    const int h = b & 7;

    for (int jj = j0; jj < nglob; jj += 32) {
      const int i = g[1 + jj];
      __syncthreads();
      if (t < HD) S.qrow[t] = q[((size_t)h * SEQ + i) * HD + t];
      __syncthreads();

      float lmax = -1e30f;
#pragma unroll 2
      for (int c = t; c < SEQ; c += 256) {
        const bool ok = (mask[c] != 0);
        const float* kr = &kx[((size_t)h * SEQ + c) * HD];
        float a0 = 0.f, a1 = 0.f, a2 = 0.f, a3 = 0.f;
#pragma unroll
        for (int d = 0; d < HD; d += 4) {
          const float4 kv = *(const float4*)&kr[d];
          const float4 qv = *(const float4*)&S.qrow[d];
          a0 = fmaf(qv.x, kv.x, a0);
          a1 = fmaf(qv.y, kv.y, a1);
          a2 = fmaf(qv.z, kv.z, a2);
          a3 = fmaf(qv.w, kv.w, a3);
        }
        const float s = ok ? ((a0 + a1) + (a2 + a3)) : -1e30f;
        lmax = fmaxf(lmax, s);
        S.sc[c] = s;
      }
      const float wm = wave_max(lmax);
      if ((t & 63) == 0) S.red[t >> 6] = wm;
      __syncthreads();
      const float rmax = fmaxf(fmaxf(S.red[0], S.red[1]), fmaxf(S.red[2], S.red[3]));

      float lsum = 0.f;
#pragma unroll 2
      for (int c = t; c < SEQ; c += 256) {
        const float s = S.sc[c];
        const float pp = (s > -1e29f) ? __expf(s - rmax) : 0.0f;
        S.sc[c] = pp;
        lsum += pp;
      }
      const float wsum = wave_sum(lsum);
      __syncthreads();
      if ((t & 63) == 0) S.red[4 + (t >> 6)] = wsum;
      __syncthreads();
      const float rsum = (S.red[4] + S.red[5]) + (S.red[6] + S.red[7]);
      const float inv = 1.0f / rsum;

      float* __restrict__ arow = attn + (size_t)h * SEQ * SEQ + (size_t)i * SEQ;
      __syncthreads();
      for (int c4 = t; c4 < 512; c4 += 256) {
        f32x4 pv;
        pv[0] = S.sc[c4 * 4 + 0] * inv;
        pv[1] = S.sc[c4 * 4 + 1] * inv;
        pv[2] = S.sc[c4 * 4 + 2] * inv;
        pv[3] = S.sc[c4 * 4 + 3] * inv;
        *(f32x4*)&arow[c4 * 4] = pv;
      }
    }
    return;
  }

  // ============ GLOBAL branch: out rows for mi==-1 ============
  {
    const int b = bid - 256;
    const int j0 = b >> 3;
    const int h = b & 7;

    for (int jj = j0; jj < nglob; jj += 32) {
      const int i = g[1 + jj];
      __syncthreads();
      if (t < HD) S.qrow[t] = qg[((size_t)h * SEQ + i) * HD + t];
      __syncthreads();

      float lmax = -1e30f;
#pragma unroll 2
      for (int c = t; c < SEQ; c += 256) {
        const bool ok = (mask[c] != 0);
        const float* kr = &kg[((size_t)h * SEQ + c) * HD];
        float a0 = 0.f, a1 = 0.f, a2 = 0.f, a3 = 0.f;
#pragma unroll
        for (int d = 0; d < HD; d += 4) {
          const float4 kv = *(const float4*)&kr[d];
          const float4 qv = *(const float4*)&S.qrow[d];
          a0 = fmaf(qv.x, kv.x, a0);
          a1 = fmaf(qv.y, kv.y, a1);
          a2 = fmaf(qv.z, kv.z, a2);
          a3 = fmaf(qv.w, kv.w, a3);
        }
        const float s = ok ? ((a0 + a1) + (a2 + a3)) : -1e30f;
        lmax = fmaxf(lmax, s);
        S.sc[c] = s;
      }
      const float wm = wave_max(lmax);
      if ((t & 63) == 0) S.red[t >> 6] = wm;
      __syncthreads();
      const float rmax = fmaxf(fmaxf(S.red[0], S.red[1]), fmaxf(S.red[2], S.red[3]));

      float lsum = 0.f;
#pragma unroll 2
      for (int c = t; c < SEQ; c += 256) {
        const float s = S.sc[c];
        const float pp = (s > -1e29f) ? __expf(s - rmax) : 0.0f;
        S.sc[c] = pp;
        lsum += pp;
      }
      const float wsum = wave_sum(lsum);
      __syncthreads();
      if ((t & 63) == 0) S.red[4 + (t >> 6)] = wsum;
      __syncthreads();
      const float rsum = (S.red[4] + S.red[5]) + (S.red[6] + S.red[7]);
      const float inv = 1.0f / rsum;

      const int wv = t >> 6;
      const int d = t & 63;
      float ctx = 0.f;
#pragma unroll 8
      for (int c = wv; c < SEQ; c += 4) {
        ctx = fmaf(S.sc[c], vg[((size_t)h * SEQ + c) * HD + d], ctx);
      }
      S.ctxp[wv][d] = ctx;
      __syncthreads();
      if (t < HD) {
        const float r =
            ((S.ctxp[0][t] + S.ctxp[1][t]) + (S.ctxp[2][t] + S.ctxp[3][t])) * inv;
        out[(size_t)i * DIM + h * HD + t] = r;
      }
    }
  }
}

// ---------------- host ----------------
extern "C" void kernel_launch(void* const* d_in, const int* in_sizes, int n_in,
                              void* d_out, int out_size, void* d_ws, size_t ws_size,
                              hipStream_t stream) {
  const float* hs = (const float*)d_in[0];
  const int* mask = (const int*)d_in[13];

  float* q  = (float*)d_ws;                      // 6 x 4MB fp32 projections
  float* kx = q  + (size_t)SEQ * DIM;
  float* vx = kx + (size_t)SEQ * DIM;            // (vx fp32 unused; slot kept)
  float* qg = vx + (size_t)SEQ * DIM;
  float* kg = qg + (size_t)SEQ * DIM;
  float* vg = kg + (size_t)SEQ * DIM;
  int* gcols = (int*)(vg + (size_t)SEQ * DIM);   // 16KB reserved
  unsigned short* Xcat = (unsigned short*)((char*)gcols + 16384);  // 6MB
  unsigned short* Wcat0 = Xcat + (size_t)SEQ * KCAT;               // 9MB
  unsigned short* qbb = Wcat0 + (size_t)6 * DIM * KCAT;            // 3 x 2MB bf16
  unsigned short* kbb = qbb + (size_t)SEQ * DIM;
  unsigned short* vbb = kbb + (size_t)SEQ * DIM;

  float* out  = (float*)d_out;            // [1,S,DIM]
  float* attn = out + (size_t)SEQ * DIM;  // [1,H,S,S] -- filled by prep+proj

  WArgs wa;
  PMArgs pm;
  float* pouts[6] = {q, kx, nullptr, qg, kg, vg};  // vx fp32 dead -> skip
  unsigned short* poutb[6] = {qbb, kbb, vbb, nullptr, nullptr, nullptr};
  for (int p = 0; p < 6; ++p) {
    wa.W[p] = (const float*)d_in[1 + 2 * p];
    wa.Wc[p] = Wcat0 + (size_t)p * DIM * KCAT;
    pm.Wc[p] = wa.Wc[p];
    pm.b[p] = (const float*)d_in[2 + 2 * p];
    pm.out[p] = pouts[p];
    pm.outb[p] = poutb[p];
  }

  hipLaunchKernelGGL(prep_kernel, dim3(3585), dim3(256), 0, stream, hs, Xcat, wa,
                     mask, gcols, attn);

  dim3 g1(SEQ / 128, DIM / 64, 7);  // z==6 plane = fill tiles 1024-2047
  hipLaunchKernelGGL(proj_mfma_kernel, g1, dim3(256), 0, stream, Xcat, pm, attn);

  hipLaunchKernelGGL(attn_fused_kernel, dim3(1024), dim3(256), 0, stream, qbb, kbb,
                     vbb, q, kx, qg, kg, vg, mask, gcols, out, attn);
}